// Round 5
// baseline (55.149 us; speedup 1.0000x reference)
//
#include <hip/hip_runtime.h>
#include <hip/hip_bf16.h>

#define B_TOT 16384

typedef __bf16 bf16x8 __attribute__((ext_vector_type(8)));
typedef __bf16 bf16x4 __attribute__((ext_vector_type(4)));
typedef float  f32x4  __attribute__((ext_vector_type(4)));

// ---- workspace layout (bytes) ----
// wp0: [17 ksteps][8 nblk][64 lanes][8 bf16]  K-map: k<400 img, 400..415 zero, 416..543 Whh0
// wp1: [ 8 ksteps][8 nblk][64 lanes][8 bf16]  k<128 Wih1, 128..255 Whh1
// wph: [ 4 ksteps][64 lanes][8 bf16]          W_cls|W_act padded to N=16
// Xp : [16384][416] bf16 packed crop (400 crop + 16 zero pad)
#define NG0 (17*8*64)
#define NG1 (8*8*64)
#define NGH (4*64)
#define WP0_OFF  0
#define WP1_OFF  (NG0*16)
#define WPH_OFF  (WP1_OFF + NG1*16)
#define BIAS0_OFF (WPH_OFF + NGH*16)
#define BIAS1_OFF (BIAS0_OFF + 512)
#define BIASH_OFF (BIAS1_OFF + 512)
#define XP_OFF   (1<<20)
#define XPSTR    416
#define PREP_BLOCKS 53

__device__ __forceinline__ float fast_tanh(float x) {
    float cx = fminf(fmaxf(x, -9.f), 9.f);
    float t = __builtin_amdgcn_exp2f(cx * 2.8853900817779268f);
    return 1.f - 2.f * __builtin_amdgcn_rcpf(t + 1.f);
}

// ============ kernel 1: weight prepack (blocks 0..52) + crop gather/pack ============
__global__ __launch_bounds__(256) void gather_prepack(
    const float* __restrict__ image, const int* __restrict__ center,
    const float* __restrict__ Wih0, const float* __restrict__ Whh0,
    const float* __restrict__ Wih1, const float* __restrict__ Whh1,
    const float* __restrict__ Wcls, const float* __restrict__ Wact,
    const float* __restrict__ bih0, const float* __restrict__ bhh0,
    const float* __restrict__ bih1, const float* __restrict__ bhh1,
    const float* __restrict__ bcls, const float* __restrict__ bact,
    char* __restrict__ ws)
{
    __shared__ __align__(16) __bf16 gx[4 * 1024];   // 4 waves x 2 samples x 512
    const int t = threadIdx.x;

    if (blockIdx.x < PREP_BLOCKS) {
        int idx = blockIdx.x * 256 + t;
        __bf16* wp0 = (__bf16*)(ws + WP0_OFF);
        __bf16* wp1 = (__bf16*)(ws + WP1_OFF);
        __bf16* wph = (__bf16*)(ws + WPH_OFF);
        float* bias0 = (float*)(ws + BIAS0_OFF);
        float* bias1 = (float*)(ws + BIAS1_OFF);
        float* biash = (float*)(ws + BIASH_OFF);

        if (idx < NG0) {
            int lane = idx & 63, g = idx >> 6, s = g >> 3, nb = g & 7;
            int n = nb * 16 + (lane & 15);
            int kb = s * 32 + (lane >> 4) * 8;
            bf16x8 v;
            #pragma unroll
            for (int j = 0; j < 8; ++j) {
                int k = kb + j;
                float x = 0.f;
                if (k < 400)       x = Wih0[n * 400 + k];
                else if (k >= 416) x = Whh0[n * 128 + (k - 416)];
                v[j] = (__bf16)x;
            }
            *(bf16x8*)(wp0 + (size_t)idx * 8) = v;
        } else if (idx < NG0 + NG1) {
            int i2 = idx - NG0;
            int lane = i2 & 63, g = i2 >> 6, s = g >> 3, nb = g & 7;
            int n = nb * 16 + (lane & 15);
            int kb = s * 32 + (lane >> 4) * 8;
            bf16x8 v;
            #pragma unroll
            for (int j = 0; j < 8; ++j) {
                int k = kb + j;
                float x = (k < 128) ? Wih1[n * 128 + k] : Whh1[n * 128 + (k - 128)];
                v[j] = (__bf16)x;
            }
            *(bf16x8*)(wp1 + (size_t)i2 * 8) = v;
        } else if (idx < NG0 + NG1 + NGH) {
            int i3 = idx - NG0 - NG1;
            int lane = i3 & 63, s = i3 >> 6;
            int n = lane & 15;
            int kb = s * 32 + (lane >> 4) * 8;
            bf16x8 v;
            #pragma unroll
            for (int j = 0; j < 8; ++j) {
                int k = kb + j;
                float x = 0.f;
                if (n < 10)      x = Wcls[n * 128 + k];
                else if (n < 12) x = Wact[(n - 10) * 128 + k];
                v[j] = (__bf16)x;
            }
            *(bf16x8*)(wph + (size_t)i3 * 8) = v;
        } else {
            int i4 = idx - NG0 - NG1 - NGH;
            if (i4 < 128) bias0[i4] = bih0[i4] + bhh0[i4];
            else if (i4 < 256) { int i = i4 - 128; bias1[i] = bih1[i] + bhh1[i]; }
            else if (i4 < 272) {
                int i = i4 - 256;
                biash[i] = (i < 10) ? bcls[i] : ((i < 12) ? bact[i - 10] : 0.f);
            }
        }
        return;
    }

    // ---- gather path: wave-private, barrier-free ----
    const int bid = blockIdx.x - PREP_BLOCKS;
    const int w = t >> 6, lane = t & 63;
    const int sA = bid * 8 + w * 2, sB = sA + 1;
    __bf16* rA = gx + w * 1024;
    __bf16* rB = rA + 512;
    __bf16* Xp = (__bf16*)(ws + XP_OFF);

    // zero both 512-elem regions (64 lanes x 16B = 1024B each)
    f32x4 z = {};
    *(f32x4*)(rA + lane * 8) = z;
    *(f32x4*)(rB + lane * 8) = z;

    const int lr28 = lane / 28, lx28 = lane - lr28 * 28;  // lanes 56..63 idle
    const int cxA = center[sA * 2], cyA = center[sA * 2 + 1];
    const int cxB = center[sB * 2], cyB = center[sB * 2 + 1];
    const int rloA = max(0, cyA - 20), rhiA = min(28, cyA);
    const int rloB = max(0, cyB - 20), rhiB = min(28, cyB);
    const float* imgA = image + (size_t)sA * 784;
    const float* imgB = image + (size_t)sB * 784;

    float gA[10], gB[10];
    #pragma unroll
    for (int it = 0; it < 10; ++it) {
        int iy = rloA + lr28 + it * 2;
        gA[it] = (lr28 < 2 && iy < rhiA) ? imgA[iy * 28 + lx28] : 0.f;
    }
    #pragma unroll
    for (int it = 0; it < 10; ++it) {
        int iy = rloB + lr28 + it * 2;
        gB[it] = (lr28 < 2 && iy < rhiB) ? imgB[iy * 28 + lx28] : 0.f;
    }

    // scatter into LDS crop layout k = r*20+c
    #pragma unroll
    for (int it = 0; it < 10; ++it) {
        int iy = rloA + lr28 + it * 2;
        int r = iy - (cyA - 20), c = lx28 - (cxA - 20);
        if (lr28 < 2 && iy < rhiA && (unsigned)c < 20u)
            rA[r * 20 + c] = (__bf16)gA[it];
    }
    #pragma unroll
    for (int it = 0; it < 10; ++it) {
        int iy = rloB + lr28 + it * 2;
        int r = iy - (cyB - 20), c = lx28 - (cxB - 20);
        if (lr28 < 2 && iy < rhiB && (unsigned)c < 20u)
            rB[r * 20 + c] = (__bf16)gB[it];
    }

    // readback + coalesced packed store (52 lanes x 16B = 832B = 416 bf16)
    if (lane < 52) {
        bf16x8 vA = *(const bf16x8*)(rA + lane * 8);
        bf16x8 vB = *(const bf16x8*)(rB + lane * 8);
        *(bf16x8*)(Xp + (size_t)sA * XPSTR + lane * 8) = vA;
        *(bf16x8*)(Xp + (size_t)sB * XPSTR + lane * 8) = vB;
    }
}

// ============ kernel 2: GEMMs, A-frags direct from packed Xp / h0 ============
#define HEXSTR 136

__global__ __launch_bounds__(512, 2) void gemm_main(
    const float* __restrict__ h0, const char* __restrict__ ws,
    float* __restrict__ out)
{
    const bf16x8* wp0 = (const bf16x8*)(ws + WP0_OFF);
    const bf16x8* wp1 = (const bf16x8*)(ws + WP1_OFF);
    const bf16x8* wph = (const bf16x8*)(ws + WPH_OFF);
    const float* bias0 = (const float*)(ws + BIAS0_OFF);
    const float* bias1 = (const float*)(ws + BIAS1_OFF);
    const float* biash = (const float*)(ws + BIASH_OFF);
    const __bf16* Xp = (const __bf16*)(ws + XP_OFF);

    __shared__ __align__(16) __bf16 hex[2 * 16 * HEXSTR];
    __bf16* h1ex = hex;
    __bf16* h2ex = hex + 16 * HEXSTR;

    const int t = threadIdx.x, lane = t & 63, wn = t >> 6;
    const int qr = lane >> 4, lr = lane & 15;
    const int m0 = blockIdx.x * 16;

    // ---- A-fragments: crop X direct from packed Xp (no LDS, no barrier) ----
    const __bf16* xrow = Xp + (size_t)(m0 + lr) * XPSTR + qr * 8;
    bf16x8 xa[13];
    #pragma unroll
    for (int s = 0; s < 13; ++s) xa[s] = *(const bf16x8*)(xrow + s * 32);

    // ---- A-fragments: h0 layer0/layer1, f32 -> bf16 in-register ----
    const float* h0r0 = h0 + (size_t)(m0 + lr) * 128 + qr * 8;
    const float* h0r1 = h0r0 + (size_t)B_TOT * 128;
    bf16x8 h0a[4], h0b[4];
    #pragma unroll
    for (int s = 0; s < 4; ++s) {
        float4 fa = *(const float4*)(h0r0 + s * 32);
        float4 fb = *(const float4*)(h0r0 + s * 32 + 4);
        bf16x8 hh;
        hh[0]=(__bf16)fa.x; hh[1]=(__bf16)fa.y; hh[2]=(__bf16)fa.z; hh[3]=(__bf16)fa.w;
        hh[4]=(__bf16)fb.x; hh[5]=(__bf16)fb.y; hh[6]=(__bf16)fb.z; hh[7]=(__bf16)fb.w;
        h0a[s] = hh;
    }
    #pragma unroll
    for (int s = 0; s < 4; ++s) {
        float4 fa = *(const float4*)(h0r1 + s * 32);
        float4 fb = *(const float4*)(h0r1 + s * 32 + 4);
        bf16x8 hh;
        hh[0]=(__bf16)fa.x; hh[1]=(__bf16)fa.y; hh[2]=(__bf16)fa.z; hh[3]=(__bf16)fa.w;
        hh[4]=(__bf16)fb.x; hh[5]=(__bf16)fb.y; hh[6]=(__bf16)fb.z; hh[7]=(__bf16)fb.w;
        h0b[s] = hh;
    }

    // ---- B-fragments ----
    bf16x8 bw0[17];
    #pragma unroll
    for (int s = 0; s < 17; ++s) bw0[s] = wp0[(size_t)(s * 8 + wn) * 64 + lane];
    bf16x8 bw1[8];
    #pragma unroll
    for (int s = 0; s < 8; ++s) bw1[s] = wp1[(size_t)(s * 8 + wn) * 64 + lane];
    bf16x8 bh[4];
    if (wn == 0) {
        #pragma unroll
        for (int s = 0; s < 4; ++s) bh[s] = wph[(size_t)s * 64 + lane];
    }

    const int n = wn * 16 + lr;
    const float bv0 = bias0[n], bv1 = bias1[n];

    float* outh1 = out + (size_t)B_TOT * 12;
    float* outh2 = out + (size_t)B_TOT * 140;

    // ================= GEMM0 (no barrier needed before this) =================
    f32x4 acc0 = {};
    #pragma unroll
    for (int s = 0; s < 13; ++s)
        acc0 = __builtin_amdgcn_mfma_f32_16x16x32_bf16(xa[s], bw0[s], acc0, 0, 0, 0);
    #pragma unroll
    for (int s = 0; s < 4; ++s)
        acc0 = __builtin_amdgcn_mfma_f32_16x16x32_bf16(h0a[s], bw0[13 + s], acc0, 0, 0, 0);

    #pragma unroll
    for (int r = 0; r < 4; ++r) {
        float hv = fast_tanh(acc0[r] + bv0);
        h1ex[(qr * 4 + r) * HEXSTR + n] = (__bf16)hv;
    }
    __syncthreads();

    // ---- h1 full-line out stores (from exchange buffer) ----
    {
        int row = t >> 5, c4 = (t & 31) * 4;
        bf16x4 hv4 = *(const bf16x4*)(h1ex + row * HEXSTR + c4);
        float4 o;
        o.x = (float)hv4[0]; o.y = (float)hv4[1]; o.z = (float)hv4[2]; o.w = (float)hv4[3];
        *(float4*)(outh1 + (size_t)(m0 + row) * 128 + c4) = o;
    }

    // ================= GEMM1 =================
    f32x4 acc1 = {};
    {
        const __bf16* h1row = h1ex + lr * HEXSTR + qr * 8;
        #pragma unroll
        for (int s = 0; s < 4; ++s) {
            bf16x8 a = *(const bf16x8*)(h1row + s * 32);
            acc1 = __builtin_amdgcn_mfma_f32_16x16x32_bf16(a, bw1[s], acc1, 0, 0, 0);
        }
        #pragma unroll
        for (int s = 0; s < 4; ++s)
            acc1 = __builtin_amdgcn_mfma_f32_16x16x32_bf16(h0b[s], bw1[4 + s], acc1, 0, 0, 0);
    }
    #pragma unroll
    for (int r = 0; r < 4; ++r) {
        float hv = fast_tanh(acc1[r] + bv1);
        h2ex[(qr * 4 + r) * HEXSTR + n] = (__bf16)hv;
    }
    __syncthreads();

    // ---- h2 full-line out stores ----
    {
        int row = t >> 5, c4 = (t & 31) * 4;
        bf16x4 hv4 = *(const bf16x4*)(h2ex + row * HEXSTR + c4);
        float4 o;
        o.x = (float)hv4[0]; o.y = (float)hv4[1]; o.z = (float)hv4[2]; o.w = (float)hv4[3];
        *(float4*)(outh2 + (size_t)(m0 + row) * 128 + c4) = o;
    }

    // ---- heads (wave 0) ----
    if (wn == 0) {
        f32x4 acc2 = {};
        const __bf16* h2row = h2ex + lr * HEXSTR + qr * 8;
        #pragma unroll
        for (int s = 0; s < 4; ++s) {
            bf16x8 a = *(const bf16x8*)(h2row + s * 32);
            acc2 = __builtin_amdgcn_mfma_f32_16x16x32_bf16(a, bh[s], acc2, 0, 0, 0);
        }
        float bhd = biash[lr];
        #pragma unroll
        for (int r = 0; r < 4; ++r) {
            int mg = m0 + qr * 4 + r;
            float v = acc2[r] + bhd;
            if (lr < 10)      out[(size_t)mg * 10 + lr] = v;
            else if (lr < 12) out[(size_t)B_TOT * 10 + (size_t)mg * 2 + (lr - 10)] = v;
        }
    }
}

extern "C" void kernel_launch(void* const* d_in, const int* in_sizes, int n_in,
                              void* d_out, int out_size, void* d_ws, size_t ws_size,
                              hipStream_t stream) {
    const float* image = (const float*)d_in[0];
    const int*   center = (const int*)d_in[1];
    const float* h0   = (const float*)d_in[2];
    const float* Wih0 = (const float*)d_in[3];
    const float* bih0 = (const float*)d_in[4];
    const float* Whh0 = (const float*)d_in[5];
    const float* bhh0 = (const float*)d_in[6];
    const float* Wih1 = (const float*)d_in[7];
    const float* bih1 = (const float*)d_in[8];
    const float* Whh1 = (const float*)d_in[9];
    const float* bhh1 = (const float*)d_in[10];
    const float* Wcls = (const float*)d_in[11];
    const float* bcls = (const float*)d_in[12];
    const float* Wact = (const float*)d_in[13];
    const float* bact = (const float*)d_in[14];

    gather_prepack<<<PREP_BLOCKS + B_TOT / 8, 256, 0, stream>>>(
        image, center, Wih0, Whh0, Wih1, Whh1, Wcls, Wact,
        bih0, bhh0, bih1, bhh1, bcls, bact, (char*)d_ws);
    gemm_main<<<B_TOT / 16, 512, 0, stream>>>(h0, (const char*)d_ws, (float*)d_out);
}

// Round 7
// 38.703 us; speedup vs baseline: 1.4249x; 1.4249x over previous
//
#include <hip/hip_runtime.h>
#include <hip/hip_bf16.h>

#define B_TOT 16384

typedef __bf16 bf16x8 __attribute__((ext_vector_type(8)));
typedef __bf16 bf16x4 __attribute__((ext_vector_type(4)));
typedef float  f32x4  __attribute__((ext_vector_type(4)));

// ---- workspace layout (bytes) ----
// wp0: [17 ksteps][8 nblk][64 lanes][8 bf16]  K-map: k<400 img, 400..415 zero, 416..543 Whh0
// wp1: [ 8 ksteps][8 nblk][64 lanes][8 bf16]  k<128 Wih1, 128..255 Whh1
// wph: [ 4 ksteps][64 lanes][8 bf16]          W_cls|W_act padded to N=16
// Xp : [16384][416] bf16 packed crop
// Hp : [2][16384][128] bf16 packed h0
#define NG0 (17*8*64)
#define NG1 (8*8*64)
#define NGH (4*64)
#define WP0_OFF  0
#define WP1_OFF  (NG0*16)
#define WPH_OFF  (WP1_OFF + NG1*16)
#define BIAS0_OFF (WPH_OFF + NGH*16)
#define BIAS1_OFF (BIAS0_OFF + 512)
#define BIASH_OFF (BIAS1_OFF + 512)
#define XP_OFF   (1<<20)
#define XPSTR    416
#define HP_OFF   (XP_OFF + (size_t)B_TOT * XPSTR * 2)
#define PREP_BLOCKS 53
#define GATHER_BLOCKS (B_TOT / 8)
#define H0PACK_BLOCKS 2048

__device__ __forceinline__ float fast_tanh(float x) {
    float cx = fminf(fmaxf(x, -9.f), 9.f);
    float t = __builtin_amdgcn_exp2f(cx * 2.8853900817779268f);
    return 1.f - 2.f * __builtin_amdgcn_rcpf(t + 1.f);
}

// ============ kernel 1: prepack (blocks 0..52) + crop gather + h0 pack ============
__global__ __launch_bounds__(256) void gather_prepack(
    const float* __restrict__ image, const int* __restrict__ center,
    const float* __restrict__ h0,
    const float* __restrict__ Wih0, const float* __restrict__ Whh0,
    const float* __restrict__ Wih1, const float* __restrict__ Whh1,
    const float* __restrict__ Wcls, const float* __restrict__ Wact,
    const float* __restrict__ bih0, const float* __restrict__ bhh0,
    const float* __restrict__ bih1, const float* __restrict__ bhh1,
    const float* __restrict__ bcls, const float* __restrict__ bact,
    char* __restrict__ ws)
{
    __shared__ __align__(16) __bf16 gx[4 * 1024];
    const int t = threadIdx.x;

    if (blockIdx.x < PREP_BLOCKS) {
        int idx = blockIdx.x * 256 + t;
        __bf16* wp0 = (__bf16*)(ws + WP0_OFF);
        __bf16* wp1 = (__bf16*)(ws + WP1_OFF);
        __bf16* wph = (__bf16*)(ws + WPH_OFF);
        float* bias0 = (float*)(ws + BIAS0_OFF);
        float* bias1 = (float*)(ws + BIAS1_OFF);
        float* biash = (float*)(ws + BIASH_OFF);

        if (idx < NG0) {
            int lane = idx & 63, g = idx >> 6, s = g >> 3, nb = g & 7;
            int n = nb * 16 + (lane & 15);
            int kb = s * 32 + (lane >> 4) * 8;
            bf16x8 v;
            #pragma unroll
            for (int j = 0; j < 8; ++j) {
                int k = kb + j;
                float x = 0.f;
                if (k < 400)       x = Wih0[n * 400 + k];
                else if (k >= 416) x = Whh0[n * 128 + (k - 416)];
                v[j] = (__bf16)x;
            }
            *(bf16x8*)(wp0 + (size_t)idx * 8) = v;
        } else if (idx < NG0 + NG1) {
            int i2 = idx - NG0;
            int lane = i2 & 63, g = i2 >> 6, s = g >> 3, nb = g & 7;
            int n = nb * 16 + (lane & 15);
            int kb = s * 32 + (lane >> 4) * 8;
            bf16x8 v;
            #pragma unroll
            for (int j = 0; j < 8; ++j) {
                int k = kb + j;
                float x = (k < 128) ? Wih1[n * 128 + k] : Whh1[n * 128 + (k - 128)];
                v[j] = (__bf16)x;
            }
            *(bf16x8*)(wp1 + (size_t)i2 * 8) = v;
        } else if (idx < NG0 + NG1 + NGH) {
            int i3 = idx - NG0 - NG1;
            int lane = i3 & 63, s = i3 >> 6;
            int n = lane & 15;
            int kb = s * 32 + (lane >> 4) * 8;
            bf16x8 v;
            #pragma unroll
            for (int j = 0; j < 8; ++j) {
                int k = kb + j;
                float x = 0.f;
                if (n < 10)      x = Wcls[n * 128 + k];
                else if (n < 12) x = Wact[(n - 10) * 128 + k];
                v[j] = (__bf16)x;
            }
            *(bf16x8*)(wph + (size_t)i3 * 8) = v;
        } else {
            int i4 = idx - NG0 - NG1 - NGH;
            if (i4 < 128) bias0[i4] = bih0[i4] + bhh0[i4];
            else if (i4 < 256) { int i = i4 - 128; bias1[i] = bih1[i] + bhh1[i]; }
            else if (i4 < 272) {
                int i = i4 - 256;
                biash[i] = (i < 10) ? bcls[i] : ((i < 12) ? bact[i - 10] : 0.f);
            }
        }
        return;
    }

    const int bid = blockIdx.x - PREP_BLOCKS;
    if (bid < GATHER_BLOCKS) {
        // ---- crop gather: wave-private, barrier-free ----
        const int w = t >> 6, lane = t & 63;
        const int sA = bid * 8 + w * 2, sB = sA + 1;
        __bf16* rA = gx + w * 1024;
        __bf16* rB = rA + 512;
        __bf16* Xp = (__bf16*)(ws + XP_OFF);

        f32x4 z = {};
        *(f32x4*)(rA + lane * 8) = z;
        *(f32x4*)(rB + lane * 8) = z;

        const int lr28 = lane / 28, lx28 = lane - lr28 * 28;
        const int cxA = center[sA * 2], cyA = center[sA * 2 + 1];
        const int cxB = center[sB * 2], cyB = center[sB * 2 + 1];
        const int rloA = max(0, cyA - 20), rhiA = min(28, cyA);
        const int rloB = max(0, cyB - 20), rhiB = min(28, cyB);
        const float* imgA = image + (size_t)sA * 784;
        const float* imgB = image + (size_t)sB * 784;

        float gA[10], gB[10];
        #pragma unroll
        for (int it = 0; it < 10; ++it) {
            int iy = rloA + lr28 + it * 2;
            gA[it] = (lr28 < 2 && iy < rhiA) ? imgA[iy * 28 + lx28] : 0.f;
        }
        #pragma unroll
        for (int it = 0; it < 10; ++it) {
            int iy = rloB + lr28 + it * 2;
            gB[it] = (lr28 < 2 && iy < rhiB) ? imgB[iy * 28 + lx28] : 0.f;
        }
        #pragma unroll
        for (int it = 0; it < 10; ++it) {
            int iy = rloA + lr28 + it * 2;
            int r = iy - (cyA - 20), c = lx28 - (cxA - 20);
            if (lr28 < 2 && iy < rhiA && (unsigned)c < 20u)
                rA[r * 20 + c] = (__bf16)gA[it];
        }
        #pragma unroll
        for (int it = 0; it < 10; ++it) {
            int iy = rloB + lr28 + it * 2;
            int r = iy - (cyB - 20), c = lx28 - (cxB - 20);
            if (lr28 < 2 && iy < rhiB && (unsigned)c < 20u)
                rB[r * 20 + c] = (__bf16)gB[it];
        }
        if (lane < 52) {
            bf16x8 vA = *(const bf16x8*)(rA + lane * 8);
            bf16x8 vB = *(const bf16x8*)(rB + lane * 8);
            *(bf16x8*)(Xp + (size_t)sA * XPSTR + lane * 8) = vA;
            *(bf16x8*)(Xp + (size_t)sB * XPSTR + lane * 8) = vB;
        }
        return;
    }

    // ---- h0 pack: f32 -> bf16, 8 elems/thread, streaming ----
    {
        int idx = (bid - GATHER_BLOCKS) * 256 + t;      // 0 .. 524287
        size_t base = (size_t)idx * 8;                  // over 2*16384*128 elems
        float4 a = *(const float4*)(h0 + base);
        float4 b = *(const float4*)(h0 + base + 4);
        bf16x8 v;
        v[0]=(__bf16)a.x; v[1]=(__bf16)a.y; v[2]=(__bf16)a.z; v[3]=(__bf16)a.w;
        v[4]=(__bf16)b.x; v[5]=(__bf16)b.y; v[6]=(__bf16)b.z; v[7]=(__bf16)b.w;
        *(bf16x8*)((__bf16*)(ws + HP_OFF) + base) = v;
    }
}

// ============ kernel 2: GEMMs — in-loop loads, small live set, high TLP ============
#define HEXSTR 136

__global__ __launch_bounds__(256) void gemm_main(
    const char* __restrict__ ws, float* __restrict__ out)
{
    const bf16x8* wp0 = (const bf16x8*)(ws + WP0_OFF);
    const bf16x8* wp1 = (const bf16x8*)(ws + WP1_OFF);
    const bf16x8* wph = (const bf16x8*)(ws + WPH_OFF);
    const float* bias0 = (const float*)(ws + BIAS0_OFF);
    const float* bias1 = (const float*)(ws + BIAS1_OFF);
    const float* biash = (const float*)(ws + BIASH_OFF);
    const __bf16* Xp = (const __bf16*)(ws + XP_OFF);
    const __bf16* Hp = (const __bf16*)(ws + HP_OFF);

    __shared__ __align__(16) __bf16 hex[2 * 16 * HEXSTR];
    __bf16* h1ex = hex;
    __bf16* h2ex = hex + 16 * HEXSTR;

    const int t = threadIdx.x, lane = t & 63, wn = t >> 6;   // 4 waves, 32 cols each
    const int qr = lane >> 4, lr = lane & 15;
    const int m0 = blockIdx.x * 16;

    const __bf16* xrow = Xp + (size_t)(m0 + lr) * XPSTR + qr * 8;
    const __bf16* h0r0 = Hp + (size_t)(m0 + lr) * 128 + qr * 8;
    const __bf16* h0r1 = h0r0 + (size_t)B_TOT * 128;

    float* outh1 = out + (size_t)B_TOT * 12;
    float* outh2 = out + (size_t)B_TOT * 140;

    // ================= GEMM0: crop part (k-steps 0..12) + h0_0 part (13..16) =========
    f32x4 acc0[2] = {};
    #pragma unroll 4
    for (int s = 0; s < 13; ++s) {
        bf16x8 a  = *(const bf16x8*)(xrow + s * 32);
        bf16x8 b0 = wp0[(size_t)(s * 8 + wn * 2 + 0) * 64 + lane];
        bf16x8 b1 = wp0[(size_t)(s * 8 + wn * 2 + 1) * 64 + lane];
        acc0[0] = __builtin_amdgcn_mfma_f32_16x16x32_bf16(a, b0, acc0[0], 0, 0, 0);
        acc0[1] = __builtin_amdgcn_mfma_f32_16x16x32_bf16(a, b1, acc0[1], 0, 0, 0);
    }
    #pragma unroll
    for (int s = 0; s < 4; ++s) {
        bf16x8 a  = *(const bf16x8*)(h0r0 + s * 32);
        bf16x8 b0 = wp0[(size_t)((13 + s) * 8 + wn * 2 + 0) * 64 + lane];
        bf16x8 b1 = wp0[(size_t)((13 + s) * 8 + wn * 2 + 1) * 64 + lane];
        acc0[0] = __builtin_amdgcn_mfma_f32_16x16x32_bf16(a, b0, acc0[0], 0, 0, 0);
        acc0[1] = __builtin_amdgcn_mfma_f32_16x16x32_bf16(a, b1, acc0[1], 0, 0, 0);
    }
    #pragma unroll
    for (int f = 0; f < 2; ++f) {
        int n = wn * 32 + f * 16 + lr;
        float bv = bias0[n];
        #pragma unroll
        for (int r = 0; r < 4; ++r)
            h1ex[(qr * 4 + r) * HEXSTR + n] = (__bf16)fast_tanh(acc0[f][r] + bv);
    }

    // ---- GEMM1 part A: h0_1 contribution (k-steps 4..7) — independent of h1 ----
    f32x4 acc1[2] = {};
    #pragma unroll
    for (int s = 0; s < 4; ++s) {
        bf16x8 a  = *(const bf16x8*)(h0r1 + s * 32);
        bf16x8 b0 = wp1[(size_t)((4 + s) * 8 + wn * 2 + 0) * 64 + lane];
        bf16x8 b1 = wp1[(size_t)((4 + s) * 8 + wn * 2 + 1) * 64 + lane];
        acc1[0] = __builtin_amdgcn_mfma_f32_16x16x32_bf16(a, b0, acc1[0], 0, 0, 0);
        acc1[1] = __builtin_amdgcn_mfma_f32_16x16x32_bf16(a, b1, acc1[1], 0, 0, 0);
    }
    __syncthreads();

    // ---- h1 full-line out stores ----
    #pragma unroll
    for (int it = 0; it < 2; ++it) {
        int row = (t >> 5) + it * 8, c4 = (t & 31) * 4;
        bf16x4 hv4 = *(const bf16x4*)(h1ex + row * HEXSTR + c4);
        float4 o;
        o.x = (float)hv4[0]; o.y = (float)hv4[1]; o.z = (float)hv4[2]; o.w = (float)hv4[3];
        *(float4*)(outh1 + (size_t)(m0 + row) * 128 + c4) = o;
    }

    // ---- GEMM1 part B: h1 contribution (k-steps 0..3) from LDS ----
    {
        const __bf16* h1row = h1ex + lr * HEXSTR + qr * 8;
        #pragma unroll
        for (int s = 0; s < 4; ++s) {
            bf16x8 a  = *(const bf16x8*)(h1row + s * 32);
            bf16x8 b0 = wp1[(size_t)(s * 8 + wn * 2 + 0) * 64 + lane];
            bf16x8 b1 = wp1[(size_t)(s * 8 + wn * 2 + 1) * 64 + lane];
            acc1[0] = __builtin_amdgcn_mfma_f32_16x16x32_bf16(a, b0, acc1[0], 0, 0, 0);
            acc1[1] = __builtin_amdgcn_mfma_f32_16x16x32_bf16(a, b1, acc1[1], 0, 0, 0);
        }
    }
    #pragma unroll
    for (int f = 0; f < 2; ++f) {
        int n = wn * 32 + f * 16 + lr;
        float bv = bias1[n];
        #pragma unroll
        for (int r = 0; r < 4; ++r)
            h2ex[(qr * 4 + r) * HEXSTR + n] = (__bf16)fast_tanh(acc1[f][r] + bv);
    }
    __syncthreads();

    // ---- h2 full-line out stores ----
    #pragma unroll
    for (int it = 0; it < 2; ++it) {
        int row = (t >> 5) + it * 8, c4 = (t & 31) * 4;
        bf16x4 hv4 = *(const bf16x4*)(h2ex + row * HEXSTR + c4);
        float4 o;
        o.x = (float)hv4[0]; o.y = (float)hv4[1]; o.z = (float)hv4[2]; o.w = (float)hv4[3];
        *(float4*)(outh2 + (size_t)(m0 + row) * 128 + c4) = o;
    }

    // ---- heads (wave 0) ----
    if (wn == 0) {
        f32x4 acc2 = {};
        const __bf16* h2row = h2ex + lr * HEXSTR + qr * 8;
        #pragma unroll
        for (int s = 0; s < 4; ++s) {
            bf16x8 a = *(const bf16x8*)(h2row + s * 32);
            bf16x8 b = wph[(size_t)s * 64 + lane];
            acc2 = __builtin_amdgcn_mfma_f32_16x16x32_bf16(a, b, acc2, 0, 0, 0);
        }
        float bhd = biash[lr];
        #pragma unroll
        for (int r = 0; r < 4; ++r) {
            int mg = m0 + qr * 4 + r;
            float v = acc2[r] + bhd;
            if (lr < 10)      out[(size_t)mg * 10 + lr] = v;
            else if (lr < 12) out[(size_t)B_TOT * 10 + (size_t)mg * 2 + (lr - 10)] = v;
        }
    }
}

extern "C" void kernel_launch(void* const* d_in, const int* in_sizes, int n_in,
                              void* d_out, int out_size, void* d_ws, size_t ws_size,
                              hipStream_t stream) {
    const float* image = (const float*)d_in[0];
    const int*   center = (const int*)d_in[1];
    const float* h0   = (const float*)d_in[2];
    const float* Wih0 = (const float*)d_in[3];
    const float* bih0 = (const float*)d_in[4];
    const float* Whh0 = (const float*)d_in[5];
    const float* bhh0 = (const float*)d_in[6];
    const float* Wih1 = (const float*)d_in[7];
    const float* bih1 = (const float*)d_in[8];
    const float* Whh1 = (const float*)d_in[9];
    const float* bhh1 = (const float*)d_in[10];
    const float* Wcls = (const float*)d_in[11];
    const float* bcls = (const float*)d_in[12];
    const float* Wact = (const float*)d_in[13];
    const float* bact = (const float*)d_in[14];

    gather_prepack<<<PREP_BLOCKS + GATHER_BLOCKS + H0PACK_BLOCKS, 256, 0, stream>>>(
        image, center, h0, Wih0, Whh0, Wih1, Whh1, Wcls, Wact,
        bih0, bhh0, bih1, bhh1, bcls, bact, (char*)d_ws);
    gemm_main<<<B_TOT / 16, 256, 0, stream>>>((const char*)d_ws, (float*)d_out);
}